// Round 9
// baseline (177.534 us; speedup 1.0000x reference)
//
#include <hip/hip_runtime.h>
#include <math.h>

#define NU_F 0.0031830988618379067f
#define HS 136   // halves per H row: 17*8 -> 16B-aligned, odd 16B-stride = bank-balanced
#define TANH_C 2.8853900817779268f   // 2/ln(2): tanh(x) = 1 - 2/(2^(Cx)+1)

typedef __attribute__((ext_vector_type(8))) _Float16 half8;
typedef __attribute__((ext_vector_type(4))) _Float16 half4;
typedef __attribute__((ext_vector_type(16))) float f32x16;

// tanh via exp2 + fast rcp: ~5 VALU (2 on trans pipe). inf-safe: e=inf -> 1, e=0 -> -1.
__device__ __forceinline__ float fast_tanh(float x) {
    const float e = __builtin_amdgcn_exp2f(x * TANH_C);  // e^(2x)
    const float r = __builtin_amdgcn_rcpf(e + 1.f);
    return fmaf(-2.f, r, 1.f);
}

// tanh(x + b) with b pre-scaled by TANH_C: one fma instead of add+mul.
__device__ __forceinline__ float fast_tanh_pre(float x, float b2) {
    const float e = __builtin_amdgcn_exp2f(fmaf(x, TANH_C, b2));
    const float r = __builtin_amdgcn_rcpf(e + 1.f);
    return fmaf(-2.f, r, 1.f);
}

// ---------------------------------------------------------------------------
// Weight prep: W[l][k][n] fp32 -> k-tiled fp16:
//   idx = l*16384 + (k>>4)*2048 + n*16 + (k&15)
// A wave's per-kt B-read (16 halves/lane, n-contiguous) is one 1KB block.
// ---------------------------------------------------------------------------
__global__ void prep_kernel(const float* __restrict__ W1,
                            const float* __restrict__ W2,
                            const float* __restrict__ W3,
                            _Float16* __restrict__ ws)
{
    const int g = blockIdx.x * 256 + threadIdx.x;   // 0..49151
    const int l = g >> 14;
    const int r = g & 16383;
    const int n = r & 127;
    const int k = r >> 7;
    const float* W = (l == 0) ? W1 : (l == 1) ? W2 : W3;
    const float w = W[k * 128 + n];
    ws[l * 16384 + (k >> 4) * 2048 + n * 16 + (k & 15)] = (_Float16)w;
}

// ---------------------------------------------------------------------------
// M=256 amortization of the R3/R8 structure: 512-thread blocks, 8 waves.
// Wave w = (wr=w>>2, wc=w&3): rows [128wr,128wr+128) x cols [32wc,32wc+32)
// -> per-wave instruction stream identical to R8 (32 ds_read + 32 MFMA +
// same epilogue per layer), but per-block fixed costs (8 barrier events,
// input/final phase drains) amortize over 64 eq points instead of 32.
// LDS 69.6 KB -> 2 blocks/CU = 16 waves/CU (same as R8). Waves w and w+4
// duplicate B-loads (VMEM idle, L2-resident). Keeps R8's setprio + trims.
// Blocks 0..2047: equation, 64 pts (rows m = 4p + channel).
// Blocks 2048..2079: init/bound forward-only, 256 pts (m = p).
// ---------------------------------------------------------------------------
__launch_bounds__(512, 4)
__global__ void pinn_kernel(const float* __restrict__ tx_eq,
                            const float* __restrict__ tx_init,
                            const float* __restrict__ tx_bnd,
                            const float* __restrict__ W0, const float* __restrict__ b0,
                            const float* __restrict__ b1, const float* __restrict__ b2,
                            const float* __restrict__ b3,
                            const float* __restrict__ W4, const float* __restrict__ b4,
                            const _Float16* __restrict__ wt,
                            float* __restrict__ out)
{
    __shared__ _Float16 Hh[256][HS];   // 69.6 KB, in-place across layers

    const int tid   = threadIdx.x;
    const int blk   = blockIdx.x;
    const bool is_eq = (blk < 2048);
    const int w     = tid >> 6;       // 0..7
    const int lane  = tid & 63;
    const int col   = lane & 31;
    const int khalf = lane >> 5;
    const int wc    = w & 3;
    const int rbase = 128 * (w >> 2); // row half owned by this wave
    const int ncol  = 32 * wc + col;
    const int wofs  = ncol * 16 + khalf * 8;

    // ---- earliest VMEM: the point coordinates (oldest in queue) ----
    float tv, xv;
    if (is_eq) {
        const float2 t2 = ((const float2*)tx_eq)[blk * 64 + (tid >> 3)];
        tv = t2.x; xv = t2.y;
    } else {
        const int p  = tid >> 1;                     // 0..255
        const int gp = (blk - 2048) * 256 + p;
        const float2* src = (gp < 4096) ? (const float2*)tx_init : (const float2*)tx_bnd;
        const int idx = (gp < 4096) ? gp : gp - 4096;
        const float2 t2 = src[idx];
        tv = t2.x; xv = t2.y;
    }

    // ---- layer-0 B prefetch: issued here, consumed after the input barrier ----
    const _Float16* ph = wt + wofs;
    half8 q0 = *(const half8*)(ph);
    half8 q1 = *(const half8*)(ph + 2048);
    half8 q2 = *(const half8*)(ph + 4096);
    half8 q3 = *(const half8*)(ph + 6144);
    half8 q4 = *(const half8*)(ph + 8192);
    half8 q5 = *(const half8*)(ph + 10240);
    half8 q6 = *(const half8*)(ph + 12288);
    half8 q7 = *(const half8*)(ph + 14336);

    // never-written zero C-operand (init once, reused all 3 layers)
    f32x16 Z;
    #pragma unroll
    for (int e = 0; e < 16; ++e) Z[e] = 0.f;

    // ---- input layer (K=2, pointwise, fp32) ----
    if (is_eq) {
        const int p  = tid >> 3;                 // 0..63
        const int f0 = (tid & 7) * 16;
        const int m0 = 4 * p;                    // 0..252
        #pragma unroll
        for (int half = 0; half < 2; ++half) {
            const int fb = f0 + 8 * half;
            float vch[4][8];
            #pragma unroll
            for (int j = 0; j < 8; ++j) {
                const int f = fb + j;
                const float w0v = W0[f];             // dz/dt
                const float w1v = W0[128 + f];       // dz/dx
                const float z = fmaf(tv, w0v, fmaf(xv, w1v, b0[f]));
                const float a = fast_tanh(z);
                const float s = 1.f - a * a;
                const float v2 = s * w1v;
                vch[0][j] = a;
                vch[1][j] = s * w0v;
                vch[2][j] = v2;
                vch[3][j] = ((a * v2) * w1v) * -2.f;
            }
            #pragma unroll
            for (int c = 0; c < 4; ++c) {
                half8 hh;
                #pragma unroll
                for (int j = 0; j < 8; ++j) hh[j] = (_Float16)vch[c][j];
                *(half8*)&Hh[m0 + c][fb] = hh;
            }
        }
    } else {
        const int p  = tid >> 1;                 // 0..255 == row m
        const int f0 = (tid & 1) * 64;
        #pragma unroll
        for (int g = 0; g < 8; ++g) {
            half8 hh;
            #pragma unroll
            for (int j = 0; j < 8; ++j) {
                const int f = f0 + 8 * g + j;
                hh[j] = (_Float16)fast_tanh(fmaf(tv, W0[f], fmaf(xv, W0[128 + f], b0[f])));
            }
            *(half8*)&Hh[p][f0 + 8 * g] = hh;
        }
    }
    __syncthreads();

    const float* barr[3] = {b1, b2, b3};

    #pragma unroll 1
    for (int layer = 0; layer < 3; ++layer) {
        const float bias2 = barr[layer][ncol] * TANH_C;

        f32x16 acc0, acc1, acc2, acc3;

#define KSTEP0(Q)                                                             \
        {                                                                     \
            const int k0 = khalf * 8;                                         \
            const half8 ah0 = *(const half8*)&Hh[rbase + col][k0];            \
            const half8 ah1 = *(const half8*)&Hh[rbase + 32 + col][k0];       \
            const half8 ah2 = *(const half8*)&Hh[rbase + 64 + col][k0];       \
            const half8 ah3 = *(const half8*)&Hh[rbase + 96 + col][k0];       \
            acc0 = __builtin_amdgcn_mfma_f32_32x32x16_f16(ah0, Q, Z, 0, 0, 0); \
            acc1 = __builtin_amdgcn_mfma_f32_32x32x16_f16(ah1, Q, Z, 0, 0, 0); \
            acc2 = __builtin_amdgcn_mfma_f32_32x32x16_f16(ah2, Q, Z, 0, 0, 0); \
            acc3 = __builtin_amdgcn_mfma_f32_32x32x16_f16(ah3, Q, Z, 0, 0, 0); \
        }
#define KSTEP(KT, Q)                                                          \
        {                                                                     \
            const int k0 = KT * 16 + khalf * 8;                               \
            const half8 ah0 = *(const half8*)&Hh[rbase + col][k0];            \
            const half8 ah1 = *(const half8*)&Hh[rbase + 32 + col][k0];       \
            const half8 ah2 = *(const half8*)&Hh[rbase + 64 + col][k0];       \
            const half8 ah3 = *(const half8*)&Hh[rbase + 96 + col][k0];       \
            acc0 = __builtin_amdgcn_mfma_f32_32x32x16_f16(ah0, Q, acc0, 0, 0, 0); \
            acc1 = __builtin_amdgcn_mfma_f32_32x32x16_f16(ah1, Q, acc1, 0, 0, 0); \
            acc2 = __builtin_amdgcn_mfma_f32_32x32x16_f16(ah2, Q, acc2, 0, 0, 0); \
            acc3 = __builtin_amdgcn_mfma_f32_32x32x16_f16(ah3, Q, acc3, 0, 0, 0); \
        }
        __builtin_amdgcn_s_setprio(1);
        KSTEP0(q0) KSTEP(1, q1) KSTEP(2, q2) KSTEP(3, q3)
        KSTEP(4, q4) KSTEP(5, q5) KSTEP(6, q6) KSTEP(7, q7)
        __builtin_amdgcn_s_setprio(0);
#undef KSTEP0
#undef KSTEP

        // ---- next layer's B prefetch: q-regs just consumed, reload now so
        // L2 latency hides under epilogue compute + both barriers.
        if (layer < 2) {
            ph += 16384;
            q0 = *(const half8*)(ph);
            q1 = *(const half8*)(ph + 2048);
            q2 = *(const half8*)(ph + 4096);
            q3 = *(const half8*)(ph + 6144);
            q4 = *(const half8*)(ph + 8192);
            q5 = *(const half8*)(ph + 10240);
            q6 = *(const half8*)(ph + 12288);
            q7 = *(const half8*)(ph + 14336);
        }

        // epilogue COMPUTE (registers only, before the barrier). C-layout:
        // reg group 4g..4g+3 = rows rbase+mt*32+8g+4khalf+{0..3} = the 4
        // derivative channels of one point (eq) -> chain rule in registers.
        half4 h16[4][4];
        #pragma unroll
        for (int mt = 0; mt < 4; ++mt)
            #pragma unroll
            for (int g = 0; g < 4; ++g) {
                const float A0 = (mt == 0 ? acc0 : mt == 1 ? acc1 : mt == 2 ? acc2 : acc3)[4 * g + 0];
                const float A1 = (mt == 0 ? acc0 : mt == 1 ? acc1 : mt == 2 ? acc2 : acc3)[4 * g + 1];
                const float A2 = (mt == 0 ? acc0 : mt == 1 ? acc1 : mt == 2 ? acc2 : acc3)[4 * g + 2];
                const float A3 = (mt == 0 ? acc0 : mt == 1 ? acc1 : mt == 2 ? acc2 : acc3)[4 * g + 3];
                half4 hv;
                if (is_eq) {
                    const float t = fast_tanh_pre(A0, bias2);
                    const float s = 1.f - t * t;
                    const float sA2 = s * A2;
                    hv[0] = (_Float16)t;
                    hv[1] = (_Float16)(s * A1);
                    hv[2] = (_Float16)sA2;
                    hv[3] = (_Float16)fmaf(s, A3, -2.f * ((t * sA2) * A2));
                } else {
                    hv[0] = (_Float16)fast_tanh_pre(A0, bias2);
                    hv[1] = (_Float16)fast_tanh_pre(A1, bias2);
                    hv[2] = (_Float16)fast_tanh_pre(A2, bias2);
                    hv[3] = (_Float16)fast_tanh_pre(A3, bias2);
                }
                h16[mt][g] = hv;
            }

        __syncthreads();   // all reads of H done -> in-place overwrite safe

        // epilogue STORE (the only work between the two barriers)
        #pragma unroll
        for (int mt = 0; mt < 4; ++mt)
            #pragma unroll
            for (int g = 0; g < 4; ++g) {
                const int mrow0 = rbase + mt * 32 + 8 * g + 4 * khalf;
                Hh[mrow0 + 0][ncol] = h16[mt][g][0];
                Hh[mrow0 + 1][ncol] = h16[mt][g][1];
                Hh[mrow0 + 2][ncol] = h16[mt][g][2];
                Hh[mrow0 + 3][ncol] = h16[mt][g][3];
            }
        __syncthreads();
    }

    // ---- final layer (128 -> 1): thread t reduces k-half (t&1) of row t>>1
    {
        const float b4v = b4[0];
        const int m = tid >> 1;                  // 0..255
        const int q = tid & 1;
        float dot = 0.f;
        #pragma unroll
        for (int g = 0; g < 8; ++g) {
            const int f = 64 * q + 8 * g;
            const half8 hh = *(const half8*)&Hh[m][f];
            const float4 wa = *(const float4*)&W4[f];
            const float4 wb = *(const float4*)&W4[f + 4];
            dot = fmaf((float)hh[0], wa.x, dot);
            dot = fmaf((float)hh[1], wa.y, dot);
            dot = fmaf((float)hh[2], wa.z, dot);
            dot = fmaf((float)hh[3], wa.w, dot);
            dot = fmaf((float)hh[4], wb.x, dot);
            dot = fmaf((float)hh[5], wb.y, dot);
            dot = fmaf((float)hh[6], wb.z, dot);
            dot = fmaf((float)hh[7], wb.w, dot);
        }
        dot += __shfl_xor(dot, 1);   // full row-dot at both lanes of the pair

        if (is_eq) {
            // wave w holds rows [32w,32w+32) = points [8w,8w+8);
            // row r of point pl (=4pl+c) sits at lanes 8pl+2c (+q).
            const int base = (lane & 7) * 8;
            const float uu   = __shfl(dot, base + 0) + b4v;
            const float utv  = __shfl(dot, base + 2);
            const float uxv  = __shfl(dot, base + 4);
            const float uxxv = __shfl(dot, base + 6);
            if (lane < 8)
                out[blk * 64 + 8 * w + lane] = fmaf(uu, uxv, utv) - NU_F * uxxv;
        } else {
            if (q == 0)
                out[131072 + (blk - 2048) * 256 + m] = dot + b4v;
        }
    }
}

extern "C" void kernel_launch(void* const* d_in, const int* in_sizes, int n_in,
                              void* d_out, int out_size, void* d_ws, size_t ws_size,
                              hipStream_t stream)
{
    const float* tx_eq   = (const float*)d_in[0];
    const float* tx_init = (const float*)d_in[1];
    const float* tx_bnd  = (const float*)d_in[2];
    const float* W0 = (const float*)d_in[3];
    const float* b0 = (const float*)d_in[4];
    const float* W1 = (const float*)d_in[5];
    const float* b1 = (const float*)d_in[6];
    const float* W2 = (const float*)d_in[7];
    const float* b2 = (const float*)d_in[8];
    const float* W3 = (const float*)d_in[9];
    const float* b3 = (const float*)d_in[10];
    const float* W4 = (const float*)d_in[11];
    const float* b4 = (const float*)d_in[12];
    float* out = (float*)d_out;
    _Float16* wt = (_Float16*)d_ws;   // needs 98304 B

    hipLaunchKernelGGL(prep_kernel, dim3(192), dim3(256), 0, stream, W1, W2, W3, wt);
    // 2048 eq blocks (64 pts) + 32 ib blocks (256 pts)
    hipLaunchKernelGGL(pinn_kernel, dim3(2080), dim3(512), 0, stream,
                       tx_eq, tx_init, tx_bnd, W0, b0, b1, b2, b3, W4, b4,
                       (const _Float16*)wt, out);
}

// Round 10
// 176.682 us; speedup vs baseline: 1.0048x; 1.0048x over previous
//
#include <hip/hip_runtime.h>
#include <math.h>

#define NU_F 0.0031830988618379067f
#define HS 136   // halves per H row: 17*8 -> 16B-aligned, odd 16B-stride = bank-balanced
#define TANH_C 2.8853900817779268f   // 2/ln(2): tanh(x) = 1 - 2/(2^(Cx)+1)

typedef __attribute__((ext_vector_type(8))) _Float16 half8;
typedef __attribute__((ext_vector_type(4))) _Float16 half4;
typedef __attribute__((ext_vector_type(16))) float f32x16;

// tanh via exp2 + fast rcp: ~5 VALU (2 on trans pipe). inf-safe: e=inf -> 1, e=0 -> -1.
__device__ __forceinline__ float fast_tanh(float x) {
    const float e = __builtin_amdgcn_exp2f(x * TANH_C);  // e^(2x)
    const float r = __builtin_amdgcn_rcpf(e + 1.f);
    return fmaf(-2.f, r, 1.f);
}

// tanh(x + b) with b pre-scaled by TANH_C: one fma instead of add+mul.
__device__ __forceinline__ float fast_tanh_pre(float x, float b2) {
    const float e = __builtin_amdgcn_exp2f(fmaf(x, TANH_C, b2));
    const float r = __builtin_amdgcn_rcpf(e + 1.f);
    return fmaf(-2.f, r, 1.f);
}

// ---------------------------------------------------------------------------
// Weight prep: W[l][k][n] fp32 -> k-tiled fp16:
//   idx = l*16384 + (k>>4)*2048 + n*16 + (k&15)
// Per (nt,kt) a wave's B-frag load (16B/lane) is one contiguous 1KB block.
// ---------------------------------------------------------------------------
__global__ void prep_kernel(const float* __restrict__ W1,
                            const float* __restrict__ W2,
                            const float* __restrict__ W3,
                            _Float16* __restrict__ ws)
{
    const int g = blockIdx.x * 256 + threadIdx.x;   // 0..49151
    const int l = g >> 14;
    const int r = g & 16383;
    const int n = r & 127;
    const int k = r >> 7;
    const float* W = (l == 0) ? W1 : (l == 1) ? W2 : W3;
    const float w = W[k * 128 + n];
    ws[l * 16384 + (k >> 4) * 2048 + n * 16 + (k & 15)] = (_Float16)w;
}

// ---------------------------------------------------------------------------
// BARRIER-FREE row-ownership restructure of R8. Wave w owns rows
// [32w,32w+32) and computes ALL 128 cols (4 n-tiles, one 16-AGPR acc at a
// time). Every LDS dependency (input->layer, layer->layer, layer->final) is
// wave-internal -> ZERO __syncthreads in the whole kernel. Per layer:
//   1. own-row full-K A-frags -> 8 regs (read BEFORE stores: in-place safe)
//   2. per nt: B streamed from L1/L2 (layer's 32KB reused by all waves),
//      8 MFMA, R8's lane-local chain-rule epilogue (D: 4 channels of a
//      point = 4 consecutive regs in one lane), 16 b16 stores.
// DS reads/layer 32->8; MFMA, stores, epilogue VALU unchanged vs R8.
// Blocks 0..4095: equation, 32 pts. Blocks 4096..4159: init/bound, 128 pts.
// ---------------------------------------------------------------------------
__launch_bounds__(256, 4)
__global__ void pinn_kernel(const float* __restrict__ tx_eq,
                            const float* __restrict__ tx_init,
                            const float* __restrict__ tx_bnd,
                            const float* __restrict__ W0, const float* __restrict__ b0,
                            const float* __restrict__ b1, const float* __restrict__ b2,
                            const float* __restrict__ b3,
                            const float* __restrict__ W4, const float* __restrict__ b4,
                            const _Float16* __restrict__ wt,
                            float* __restrict__ out)
{
    __shared__ _Float16 Hh[128][HS];   // 34.8 KB; rows [32w,32w+32) private to wave w

    const int tid   = threadIdx.x;
    const int blk   = blockIdx.x;
    const bool is_eq = (blk < 4096);
    const int w     = tid >> 6;
    const int lane  = tid & 63;
    const int col   = lane & 31;
    const int khalf = lane >> 5;
    const int rbase = 32 * w;

    // ---- point coordinates ----
    float tv, xv;
    if (is_eq) {
        const float2 t2 = ((const float2*)tx_eq)[blk * 32 + (tid >> 3)];
        tv = t2.x; xv = t2.y;
    } else {
        const int p  = tid >> 1;
        const int gp = (blk - 4096) * 128 + p;
        const float2* src = (gp < 4096) ? (const float2*)tx_init : (const float2*)tx_bnd;
        const int idx = (gp < 4096) ? gp : gp - 4096;
        const float2 t2 = src[idx];
        tv = t2.x; xv = t2.y;
    }

    // never-written zero C-operand
    f32x16 Z;
    #pragma unroll
    for (int e = 0; e < 16; ++e) Z[e] = 0.f;

    // ---- input layer (K=2, pointwise, fp32) — wave-local rows ----
    if (is_eq) {
        const int p  = tid >> 3;                 // 0..31; wave w: points [8w,8w+8)
        const int f0 = (tid & 7) * 16;
        const int m0 = 4 * p;                    // rows [32w,32w+32)
        #pragma unroll
        for (int half = 0; half < 2; ++half) {
            const int fb = f0 + 8 * half;
            float vch[4][8];
            #pragma unroll
            for (int j = 0; j < 8; ++j) {
                const int f = fb + j;
                const float w0v = W0[f];             // dz/dt
                const float w1v = W0[128 + f];       // dz/dx
                const float z = fmaf(tv, w0v, fmaf(xv, w1v, b0[f]));
                const float a = fast_tanh(z);
                const float s = 1.f - a * a;
                const float v2 = s * w1v;
                vch[0][j] = a;
                vch[1][j] = s * w0v;
                vch[2][j] = v2;
                vch[3][j] = ((a * v2) * w1v) * -2.f;
            }
            #pragma unroll
            for (int c = 0; c < 4; ++c) {
                half8 hh;
                #pragma unroll
                for (int j = 0; j < 8; ++j) hh[j] = (_Float16)vch[c][j];
                *(half8*)&Hh[m0 + c][fb] = hh;
            }
        }
    } else {
        const int p  = tid >> 1;                 // 0..127 == row m (wave-local)
        const int f0 = (tid & 1) * 64;
        #pragma unroll
        for (int g = 0; g < 8; ++g) {
            half8 hh;
            #pragma unroll
            for (int j = 0; j < 8; ++j) {
                const int f = f0 + 8 * g + j;
                hh[j] = (_Float16)fast_tanh(fmaf(tv, W0[f], fmaf(xv, W0[128 + f], b0[f])));
            }
            *(half8*)&Hh[p][f0 + 8 * g] = hh;
        }
    }
    // NO __syncthreads — all H dependencies are wave-internal from here on.

    const float* barr[3] = {b1, b2, b3};
    const _Float16* wl = wt;

    #pragma unroll 1
    for (int layer = 0; layer < 3; ++layer) {
        // 1. own-row full-K A-frags into registers (before any store: the
        //    in-place overwrite is then safe — old H lives in a0..a7).
        const _Float16* ar = &Hh[rbase + col][khalf * 8];
        const half8 a0 = *(const half8*)(ar);
        const half8 a1 = *(const half8*)(ar + 16);
        const half8 a2 = *(const half8*)(ar + 32);
        const half8 a3 = *(const half8*)(ar + 48);
        const half8 a4 = *(const half8*)(ar + 64);
        const half8 a5 = *(const half8*)(ar + 80);
        const half8 a6 = *(const half8*)(ar + 96);
        const half8 a7 = *(const half8*)(ar + 112);

        const float* __restrict__ bl = barr[layer];

        // 2. per n-tile: stream B, 8 MFMAs, epilogue, store.
        #pragma unroll
        for (int nt = 0; nt < 4; ++nt) {
            const _Float16* pb = wl + nt * 512 + col * 16 + khalf * 8;
            const half8 w0_ = *(const half8*)(pb);
            const half8 w1_ = *(const half8*)(pb + 2048);
            const half8 w2_ = *(const half8*)(pb + 4096);
            const half8 w3_ = *(const half8*)(pb + 6144);
            const half8 w4_ = *(const half8*)(pb + 8192);
            const half8 w5_ = *(const half8*)(pb + 10240);
            const half8 w6_ = *(const half8*)(pb + 12288);
            const half8 w7_ = *(const half8*)(pb + 14336);
            const float bias2 = bl[32 * nt + col] * TANH_C;

            __builtin_amdgcn_s_setprio(1);
            f32x16 acc;
            acc = __builtin_amdgcn_mfma_f32_32x32x16_f16(a0, w0_, Z,   0, 0, 0);
            acc = __builtin_amdgcn_mfma_f32_32x32x16_f16(a1, w1_, acc, 0, 0, 0);
            acc = __builtin_amdgcn_mfma_f32_32x32x16_f16(a2, w2_, acc, 0, 0, 0);
            acc = __builtin_amdgcn_mfma_f32_32x32x16_f16(a3, w3_, acc, 0, 0, 0);
            acc = __builtin_amdgcn_mfma_f32_32x32x16_f16(a4, w4_, acc, 0, 0, 0);
            acc = __builtin_amdgcn_mfma_f32_32x32x16_f16(a5, w5_, acc, 0, 0, 0);
            acc = __builtin_amdgcn_mfma_f32_32x32x16_f16(a6, w6_, acc, 0, 0, 0);
            acc = __builtin_amdgcn_mfma_f32_32x32x16_f16(a7, w7_, acc, 0, 0, 0);
            __builtin_amdgcn_s_setprio(0);

            // epilogue: reg group 4g..4g+3 = rows rbase+8g+4khalf+{0..3} =
            // the 4 derivative channels of one point (eq) -> lane-local
            // chain rule, then 16 b16 stores to own rows, cols 32nt+col.
            const int nc = 32 * nt + col;
            #pragma unroll
            for (int g = 0; g < 4; ++g) {
                const float A0 = acc[4 * g + 0];
                const float A1 = acc[4 * g + 1];
                const float A2 = acc[4 * g + 2];
                const float A3 = acc[4 * g + 3];
                half4 hv;
                if (is_eq) {
                    const float t = fast_tanh_pre(A0, bias2);
                    const float s = 1.f - t * t;
                    const float sA2 = s * A2;
                    hv[0] = (_Float16)t;
                    hv[1] = (_Float16)(s * A1);
                    hv[2] = (_Float16)sA2;
                    hv[3] = (_Float16)fmaf(s, A3, -2.f * ((t * sA2) * A2));
                } else {
                    hv[0] = (_Float16)fast_tanh_pre(A0, bias2);
                    hv[1] = (_Float16)fast_tanh_pre(A1, bias2);
                    hv[2] = (_Float16)fast_tanh_pre(A2, bias2);
                    hv[3] = (_Float16)fast_tanh_pre(A3, bias2);
                }
                const int mrow0 = rbase + 8 * g + 4 * khalf;
                Hh[mrow0 + 0][nc] = hv[0];
                Hh[mrow0 + 1][nc] = hv[1];
                Hh[mrow0 + 2][nc] = hv[2];
                Hh[mrow0 + 3][nc] = hv[3];
            }
        }
        wl += 16384;
    }

    // ---- final layer (128 -> 1): wave-local rows; thread t reduces
    //      k-half (t&1) of row t>>1. No barrier needed.
    {
        const float b4v = b4[0];
        const int m = tid >> 1;          // rows [32w,32w+32)
        const int q = tid & 1;
        float dot = 0.f;
        #pragma unroll
        for (int g = 0; g < 8; ++g) {
            const int f = 64 * q + 8 * g;
            const half8 hh = *(const half8*)&Hh[m][f];
            const float4 wa = *(const float4*)&W4[f];
            const float4 wb = *(const float4*)&W4[f + 4];
            dot = fmaf((float)hh[0], wa.x, dot);
            dot = fmaf((float)hh[1], wa.y, dot);
            dot = fmaf((float)hh[2], wa.z, dot);
            dot = fmaf((float)hh[3], wa.w, dot);
            dot = fmaf((float)hh[4], wb.x, dot);
            dot = fmaf((float)hh[5], wb.y, dot);
            dot = fmaf((float)hh[6], wb.z, dot);
            dot = fmaf((float)hh[7], wb.w, dot);
        }
        dot += __shfl_xor(dot, 1);   // full row-dot at both lanes of the pair

        if (is_eq) {
            // wave w holds rows [32w,32w+32) = points [8w,8w+8);
            // row r of point pl (=4pl+c) sits at lanes 8pl+2c (+q).
            const int base = (lane & 7) * 8;
            const float uu   = __shfl(dot, base + 0) + b4v;
            const float utv  = __shfl(dot, base + 2);
            const float uxv  = __shfl(dot, base + 4);
            const float uxxv = __shfl(dot, base + 6);
            if (lane < 8)
                out[blk * 32 + 8 * w + lane] = fmaf(uu, uxv, utv) - NU_F * uxxv;
        } else {
            if (q == 0)
                out[131072 + (blk - 4096) * 128 + m] = dot + b4v;
        }
    }
}

extern "C" void kernel_launch(void* const* d_in, const int* in_sizes, int n_in,
                              void* d_out, int out_size, void* d_ws, size_t ws_size,
                              hipStream_t stream)
{
    const float* tx_eq   = (const float*)d_in[0];
    const float* tx_init = (const float*)d_in[1];
    const float* tx_bnd  = (const float*)d_in[2];
    const float* W0 = (const float*)d_in[3];
    const float* b0 = (const float*)d_in[4];
    const float* W1 = (const float*)d_in[5];
    const float* b1 = (const float*)d_in[6];
    const float* W2 = (const float*)d_in[7];
    const float* b2 = (const float*)d_in[8];
    const float* W3 = (const float*)d_in[9];
    const float* b3 = (const float*)d_in[10];
    const float* W4 = (const float*)d_in[11];
    const float* b4 = (const float*)d_in[12];
    float* out = (float*)d_out;
    _Float16* wt = (_Float16*)d_ws;   // needs 98304 B

    hipLaunchKernelGGL(prep_kernel, dim3(192), dim3(256), 0, stream, W1, W2, W3, wt);
    // 4096 eq blocks (32 pts) + 64 ib blocks (128 pts)
    hipLaunchKernelGGL(pinn_kernel, dim3(4160), dim3(256), 0, stream,
                       tx_eq, tx_init, tx_bnd, W0, b0, b1, b2, b3, W4, b4,
                       (const _Float16*)wt, out);
}